// Round 13
// baseline (166.673 us; speedup 1.0000x reference)
//
#include <hip/hip_runtime.h>

typedef unsigned short u16;
typedef __attribute__((ext_vector_type(8))) __bf16 bf16x8;
typedef __attribute__((ext_vector_type(4))) float f32x4;

__device__ __forceinline__ u16 f2bf(float f) {
  union { float f; unsigned u; } x; x.f = f;
  unsigned r = x.u + 0x7fffu + ((x.u >> 16) & 1u);
  return (u16)(r >> 16);
}

#define GLD16(g, l) __builtin_amdgcn_global_load_lds( \
    (__attribute__((address_space(1))) void*)(size_t)(g), \
    (__attribute__((address_space(3))) void*)(l), 16, 0, 0)

// ---------------------------------------------------------------------------
// Fused prep: [0,12288) x fp32->bf16; [12288,14016) Wqkv transpose+perm;
// [14016,14592) Wfc transpose.
__global__ __launch_bounds__(256) void prep(const float* __restrict__ x,
                                            u16* __restrict__ xz,
                                            const float* __restrict__ Wqkv,
                                            u16* __restrict__ wqkvT,
                                            const float* __restrict__ Wfc,
                                            u16* __restrict__ wfcT) {
  __shared__ u16 tile[32][33];
  int bid = blockIdx.x;
  if (bid < 12288) {
    int i = bid * 256 + threadIdx.x;
    float4 v = ((const float4*)x)[i];
    ushort4 o;
    o.x = f2bf(v.x); o.y = f2bf(v.y); o.z = f2bf(v.z); o.w = f2bf(v.w);
    ((ushort4*)xz)[i] = o;
    return;
  }
  const float* in; u16* out; int C, perm, b2;
  if (bid < 14016) { b2 = bid - 12288; in = Wqkv; out = wqkvT; C = 2304; perm = 1; }
  else             { b2 = bid - 14016; in = Wfc;  out = wfcT;  C = 768;  perm = 0; }
  const int R = 768;
  int tilesC = C >> 5;
  int bc = b2 % tilesC, br = b2 / tilesC;
  int tx = threadIdx.x & 31, ty = threadIdx.x >> 5;
#pragma unroll
  for (int i = 0; i < 4; ++i)
    tile[ty + i * 8][tx] = f2bf(in[(size_t)(br * 32 + ty + i * 8) * C + bc * 32 + tx]);
  __syncthreads();
#pragma unroll
  for (int i = 0; i < 4; ++i) {
    int c = bc * 32 + ty + i * 8;
    int orow;
    if (perm) {
      int which = c % 3, h = c / 288, d = (c % 288) / 3;
      orow = which * 768 + h * 96 + d;
    } else {
      orow = c;
    }
    out[(size_t)orow * R + br * 32 + tx] = tile[tx][ty + i * 8];
  }
}

// ---------------------------------------------------------------------------
// 256 x (64*NF) GEMM, BK=64, 8 waves (2 x 4), dbuf=2, 4 phases/tile:
// {ds_reads; stage-half; barrier; lgkmcnt(0)+sched_barrier; prio1 MFMA prio0;
//  barrier}, one vmcnt(0) per tile boundary. XOR-swizzled LDS (both sides).
// NF = 16-col fragments per wave (4 -> 256-wide tile, 3 -> 192-wide).
// EPI=0: bf16 store to one of {q,k,v} dense [M][768] by column region
//        (region = tc*NF/12: 768 output cols per region).
// EPI=1: fp32 store + bias; BT advanced per 1024-row batch by bstride.
template <int EPI, int NF>
__global__ __launch_bounds__(512, 2) void gemm256(
    const u16* __restrict__ A, const u16* __restrict__ BT,
    const float* __restrict__ bias, int K, int lda, int ldb, int ldc,
    int tilesN, int cpx, size_t bstride, float* __restrict__ outf,
    u16* __restrict__ q_dst, u16* __restrict__ k_dst, u16* __restrict__ v_dst) {
  __shared__ u16 As[2][16384];        // [buf][256r][64c]
  __shared__ u16 Bs[2][NF * 4096];    // [buf][64*NF r][64c]
  const int bid = blockIdx.x;
  const int swz = (bid & 7) * cpx + (bid >> 3);
  const int tr = swz / tilesN, tc = swz % tilesN;
  const int tid = threadIdx.x, lane = tid & 63, wv = tid >> 6;
  const int wr = wv >> 2, wc = wv & 3;
  const int l15 = lane & 15, lhi = lane >> 4;
  const int nt = K >> 6;
  const int region = (tc * NF) / 12;            // EPI=0: 0=q,1=k,2=v

  BT += (size_t)((unsigned)(tr * 256) >> 10) * bstride;   // per-batch B (EPI=1)

  const u16 *srcA[4], *srcB[NF];
#pragma unroll
  for (int ch = 0; ch < 4; ++ch) {
    int g = ch * 512 + tid;
    int r = g >> 3;
    int c = (g & 7) ^ ((r >> 1) & 7);
    srcA[ch] = A + (size_t)(tr * 256 + r) * lda + c * 8;
  }
#pragma unroll
  for (int ch = 0; ch < NF; ++ch) {
    int g = ch * 512 + tid;
    int r = g >> 3;
    int c = (g & 7) ^ ((r >> 1) & 7);
    srcB[ch] = BT + (size_t)(tc * (64 * NF) + r) * ldb + c * 8;
  }
  int offa[8], offb[NF];
#pragma unroll
  for (int m = 0; m < 8; ++m) {
    int r = wr * 128 + m * 16 + l15;
    offa[m] = r * 64 + (lhi ^ ((r >> 1) & 7)) * 8;
  }
#pragma unroll
  for (int n = 0; n < NF; ++n) {
    int r = wc * (16 * NF) + n * 16 + l15;
    offb[n] = r * 64 + (lhi ^ ((r >> 1) & 7)) * 8;
  }

  float bv4[NF];
#pragma unroll
  for (int n = 0; n < NF; ++n) {
    int colg = tc * (64 * NF) + wc * (16 * NF) + n * 16 + l15;
    if constexpr (EPI == 0) {
      int lcol = colg - region * 768;
      bv4[n] = bias[(lcol / 96) * 288 + (lcol % 96) * 3 + region];
    } else {
      bv4[n] = bias[colg];
    }
  }

#define STAGE_A(t_) do { u16* Ad_ = (u16*)As[(t_) & 1]; int ko_ = (t_) * 64; \
    _Pragma("unroll") for (int ch = 0; ch < 4; ++ch) \
      GLD16(srcA[ch] + ko_, Ad_ + ((ch * 512 + wv * 64) * 8)); } while (0)
#define STAGE_B(t_) do { u16* Bd_ = (u16*)Bs[(t_) & 1]; int ko_ = (t_) * 64; \
    _Pragma("unroll") for (int ch = 0; ch < NF; ++ch) \
      GLD16(srcB[ch] + ko_, Bd_ + ((ch * 512 + wv * 64) * 8)); } while (0)

  bf16x8 af[4][2], bfv[NF][2];
#define RD_A(m_, slot_) do { \
    af[slot_][0] = *(const bf16x8*)&Ab[offa[m_]]; \
    af[slot_][1] = *(const bf16x8*)&Ab[offa[m_] ^ 32]; } while (0)
#define RD_B(n_) do { \
    bfv[n_][0] = *(const bf16x8*)&Bb[offb[n_]]; \
    bfv[n_][1] = *(const bf16x8*)&Bb[offb[n_] ^ 32]; } while (0)

  f32x4 acc[8][NF] = {};
#define CLUSTER(MB, NB, NN) do { \
    __builtin_amdgcn_s_setprio(1); \
    _Pragma("unroll") for (int mm = 0; mm < 4; ++mm) \
    _Pragma("unroll") for (int nn = 0; nn < (NN); ++nn) \
    _Pragma("unroll") for (int ks = 0; ks < 2; ++ks) \
      acc[(MB) + mm][(NB) + nn] = __builtin_amdgcn_mfma_f32_16x16x32_bf16( \
          af[mm][ks], bfv[(NB) + nn][ks], acc[(MB) + mm][(NB) + nn], 0, 0, 0); \
    __builtin_amdgcn_s_setprio(0); } while (0)
#define WAIT_LGKM_PIN() do { \
    asm volatile("s_waitcnt lgkmcnt(0)" ::: "memory"); \
    __builtin_amdgcn_sched_barrier(0); } while (0)

  STAGE_A(0); STAGE_B(0);
  asm volatile("s_waitcnt vmcnt(0)" ::: "memory");
  __builtin_amdgcn_s_barrier();

  for (int t = 0; t < nt; ++t) {
    const u16* Ab = As[t & 1];
    const u16* Bb = Bs[t & 1];
    // ---- Ph0: reads A0-3,B0-1 before the barrier; stage A-half
    RD_A(0, 0); RD_A(1, 1); RD_A(2, 2); RD_A(3, 3);
    RD_B(0); RD_B(1);
    if (t + 1 < nt) STAGE_A(t + 1);
    asm volatile("s_waitcnt lgkmcnt(8)" ::: "memory");
    __builtin_amdgcn_s_barrier();
    WAIT_LGKM_PIN();
    CLUSTER(0, 0, 2);
    __builtin_amdgcn_s_barrier();
    // ---- Ph1: reads B2..NF-1; stage B-half
#pragma unroll
    for (int n = 2; n < NF; ++n) RD_B(n);
    if (t + 1 < nt) STAGE_B(t + 1);
    __builtin_amdgcn_s_barrier();
    WAIT_LGKM_PIN();
    CLUSTER(0, 2, NF - 2);
    __builtin_amdgcn_s_barrier();
    // ---- Ph2: reads A4-7
    RD_A(4, 0); RD_A(5, 1); RD_A(6, 2); RD_A(7, 3);
    __builtin_amdgcn_s_barrier();
    WAIT_LGKM_PIN();
    CLUSTER(4, 0, 2);
    __builtin_amdgcn_s_barrier();
    // ---- Ph3: last cluster; tile-boundary certification
    CLUSTER(4, 2, NF - 2);
    asm volatile("s_waitcnt vmcnt(0)" ::: "memory");
    __builtin_amdgcn_s_barrier();
  }
#undef STAGE_A
#undef STAGE_B
#undef RD_A
#undef RD_B
#undef CLUSTER
#undef WAIT_LGKM_PIN

  u16* dst16 = region == 0 ? q_dst : (region == 1 ? k_dst : v_dst);
#pragma unroll
  for (int m = 0; m < 8; ++m)
#pragma unroll
    for (int n = 0; n < NF; ++n) {
      int colg = tc * (64 * NF) + wc * (16 * NF) + n * 16 + l15;
      int lcol = colg - region * 768;
#pragma unroll
      for (int r = 0; r < 4; ++r) {
        int rowg = tr * 256 + wr * 128 + m * 16 + lhi * 4 + r;
        if constexpr (EPI == 0)
          dst16[(size_t)rowg * ldc + lcol] = f2bf(acc[m][n][r] + bv4[n]);
        else
          outf[(size_t)rowg * ldc + colg] = acc[m][n][r] + bv4[n];
      }
    }
}

// ---------------------------------------------------------------------------
// Fused K/V transpose + partial M = K^T V, split-K over n-chunks.
// Grid 512 = bh(128) x d-half(2) x chunk-half(2); 128 threads (2 waves).
// Each block processes 4 of the 8 n-chunks and writes its fp32 partial to
// Mp[c2][bh][96][96] (disjoint buffers -> no atomics, deterministic).
__global__ __launch_bounds__(128) void kvm(const u16* __restrict__ kd,
                                           const u16* __restrict__ vd,
                                           float* __restrict__ Mp) {
  __shared__ u16 kT[48][136];
  __shared__ u16 vT[96][136];
  const int bh = blockIdx.x >> 2;
  const int dh = (blockIdx.x >> 1) & 1;
  const int c2 = blockIdx.x & 1;
  const int b = bh >> 3, h = bh & 7;
  const int tid = threadIdx.x, lane = tid & 63, nh = tid >> 6;  // wave = n-half
  const int l15 = lane & 15, lhi = lane >> 4;

  f32x4 acc[3][3] = {};

  for (int c = c2 * 4; c < c2 * 4 + 4; ++c) {
    const u16* kbase = kd + ((size_t)(b * 1024 + c * 128)) * 768 + h * 96 + dh * 48;
    const u16* vbase = vd + ((size_t)(b * 1024 + c * 128)) * 768 + h * 96;
    __syncthreads();   // previous chunk's MFMA reads done before overwrite
#pragma unroll
    for (int j = 0; j < 6; ++j) {           // K-half: 128 rows x 6 granules
      int idx = j * 128 + tid;
      int n = idx / 6, gg = idx % 6;
      uint4 v = *(const uint4*)(kbase + (size_t)n * 768 + gg * 8);
      const u16* e = (const u16*)&v;
#pragma unroll
      for (int q = 0; q < 8; ++q) kT[gg * 8 + q][n] = e[q];
    }
#pragma unroll
    for (int j = 0; j < 12; ++j) {          // V: 128 rows x 12 granules
      int idx = j * 128 + tid;
      int n = idx / 12, gg = idx % 12;
      uint4 v = *(const uint4*)(vbase + (size_t)n * 768 + gg * 8);
      const u16* e = (const u16*)&v;
#pragma unroll
      for (int q = 0; q < 8; ++q) vT[gg * 8 + q][n] = e[q];
    }
    __syncthreads();
#pragma unroll
    for (int ks = 0; ks < 4; ++ks) {
      bf16x8 a[3], bv[3];
#pragma unroll
      for (int mi = 0; mi < 3; ++mi)
        a[mi] = *(const bf16x8*)&kT[mi * 16 + l15][ks * 32 + lhi * 8];
#pragma unroll
      for (int nj = 0; nj < 3; ++nj)
        bv[nj] = *(const bf16x8*)&vT[nh * 48 + nj * 16 + l15][ks * 32 + lhi * 8];
#pragma unroll
      for (int mi = 0; mi < 3; ++mi)
#pragma unroll
        for (int nj = 0; nj < 3; ++nj)
          acc[mi][nj] = __builtin_amdgcn_mfma_f32_16x16x32_bf16(a[mi], bv[nj], acc[mi][nj], 0, 0, 0);
    }
  }

  float* dst = Mp + (size_t)(c2 * 128 + bh) * 9216;
#pragma unroll
  for (int mi = 0; mi < 3; ++mi)
#pragma unroll
    for (int nj = 0; nj < 3; ++nj)
#pragma unroll
      for (int r = 0; r < 4; ++r)
        dst[(size_t)(dh * 48 + mi * 16 + lhi * 4 + r) * 96 +
            nh * 48 + nj * 16 + l15] = acc[mi][nj][r];
}

// ---------------------------------------------------------------------------
// GT[b][f][h*96+d] = sum_{d'} Wfc[h*96+d', f] * M[bh][d][d'],
// M = Mp[0] + Mp[1] (fp32 partials, summed then rounded once to bf16).
// Grid 256 = bh(128) x f-half(2); 8 waves cover 384 f-rows each block.
__global__ __launch_bounds__(512) void gkern(const u16* __restrict__ wfcT,
                                             const float* __restrict__ Mp,
                                             u16* __restrict__ GT) {
  const int bh = blockIdx.x >> 1, fh = blockIdx.x & 1;
  const int b = bh >> 3, h = bh & 7;
  const int tid = threadIdx.x, lane = tid & 63, wv = tid >> 6;
  const int l15 = lane & 15, lhi = lane >> 4;
  const float* M0 = Mp + (size_t)bh * 9216;
  const float* M1 = M0 + (size_t)128 * 9216;
  f32x4 acc[3][6] = {};
#pragma unroll
  for (int ks = 0; ks < 3; ++ks) {
    bf16x8 a[3], bv[6];
#pragma unroll
    for (int fi = 0; fi < 3; ++fi)
      a[fi] = *(const bf16x8*)(wfcT + (size_t)(fh * 384 + wv * 48 + fi * 16 + l15) * 768 +
                               h * 96 + ks * 32 + lhi * 8);
#pragma unroll
    for (int nj = 0; nj < 6; ++nj) {
      size_t mo = (size_t)(nj * 16 + l15) * 96 + ks * 32 + lhi * 8;
      float4 p0a = *(const float4*)(M0 + mo), p0b = *(const float4*)(M0 + mo + 4);
      float4 p1a = *(const float4*)(M1 + mo), p1b = *(const float4*)(M1 + mo + 4);
      u16 e[8];
      e[0] = f2bf(p0a.x + p1a.x); e[1] = f2bf(p0a.y + p1a.y);
      e[2] = f2bf(p0a.z + p1a.z); e[3] = f2bf(p0a.w + p1a.w);
      e[4] = f2bf(p0b.x + p1b.x); e[5] = f2bf(p0b.y + p1b.y);
      e[6] = f2bf(p0b.z + p1b.z); e[7] = f2bf(p0b.w + p1b.w);
      bv[nj] = *(const bf16x8*)e;
    }
#pragma unroll
    for (int fi = 0; fi < 3; ++fi)
#pragma unroll
      for (int nj = 0; nj < 6; ++nj)
        acc[fi][nj] = __builtin_amdgcn_mfma_f32_16x16x32_bf16(a[fi], bv[nj], acc[fi][nj], 0, 0, 0);
  }
#pragma unroll
  for (int fi = 0; fi < 3; ++fi)
#pragma unroll
    for (int nj = 0; nj < 6; ++nj)
#pragma unroll
      for (int r = 0; r < 4; ++r)
        GT[(size_t)b * 589824 +
           (size_t)(fh * 384 + wv * 48 + fi * 16 + lhi * 4 + r) * 768 +
           h * 96 + nj * 16 + l15] = f2bf(acc[fi][nj][r]);
}

// ---------------------------------------------------------------------------
extern "C" void kernel_launch(void* const* d_in, const int* in_sizes, int n_in,
                              void* d_out, int out_size, void* d_ws, size_t ws_size,
                              hipStream_t stream) {
  const float* x    = (const float*)d_in[0];
  const float* Wqkv = (const float*)d_in[1];
  const float* bqkv = (const float*)d_in[2];
  const float* Wfc  = (const float*)d_in[3];
  const float* bfc  = (const float*)d_in[4];
  float* out = (float*)d_out;

  char* ws = (char*)d_ws;
  size_t off = 0;
  auto alloc = [&](size_t bytes) {
    void* p = ws + off;
    off += (bytes + 255) & ~(size_t)255;
    return p;
  };
  u16* xz    = (u16*)alloc(16384ull * 768 * 2);   // x_bf16; later Mp[2][128][96][96] f32
  u16* wqkvT = (u16*)alloc(2304ull * 768 * 2);
  u16* wfcT  = (u16*)alloc(768ull * 768 * 2);
  u16* qb    = (u16*)alloc(16384ull * 768 * 2);   // Q dense
  u16* kb    = (u16*)alloc(16384ull * 768 * 2);   // K dense
  u16* vb    = (u16*)alloc(16384ull * 768 * 2);   // V dense; later GT[16][768][768]

  // fused conversions/transposes
  prep<<<14592, 256, 0, stream>>>(x, xz, Wqkv, wqkvT, Wfc, wfcT);

  // QKV projection -> dense q/k/v (256x192 tiles, 768 blocks = exactly 3/CU)
  gemm256<0, 3><<<768, 512, 0, stream>>>(xz, wqkvT, bqkv, 768, 768, 768, 768,
                                         12, 96, 0, nullptr, qb, kb, vb);

  // fused K/V transpose + split-K partial M (fp32, into dead xz region)
  kvm<<<512, 128, 0, stream>>>(kb, vb, (float*)xz);

  // GT_b = (M W_h)^T, M = sum of partials (into vb, V dense dead after kvm)
  gkern<<<256, 512, 0, stream>>>(wfcT, (const float*)xz, vb);

  // out = Q @ GT_b^T + bfc (per-batch B), 256x192 tiles -> 256 blocks, 1 round
  gemm256<1, 3><<<256, 512, 0, stream>>>(qb, vb, bfc, 768, 768, 768, 768,
                                         4, 32, 589824ull, out, nullptr, nullptr, nullptr);
}

// Round 14
// 158.966 us; speedup vs baseline: 1.0485x; 1.0485x over previous
//
#include <hip/hip_runtime.h>

typedef unsigned short u16;
typedef __attribute__((ext_vector_type(8))) __bf16 bf16x8;
typedef __attribute__((ext_vector_type(4))) float f32x4;

__device__ __forceinline__ u16 f2bf(float f) {
  union { float f; unsigned u; } x; x.f = f;
  unsigned r = x.u + 0x7fffu + ((x.u >> 16) & 1u);
  return (u16)(r >> 16);
}

#define GLD16(g, l) __builtin_amdgcn_global_load_lds( \
    (__attribute__((address_space(1))) void*)(size_t)(g), \
    (__attribute__((address_space(3))) void*)(l), 16, 0, 0)

// ---------------------------------------------------------------------------
// Fused prep: [0,12288) x fp32->bf16; [12288,14016) Wqkv transpose+perm;
// [14016,14592) Wfc transpose.
__global__ __launch_bounds__(256) void prep(const float* __restrict__ x,
                                            u16* __restrict__ xz,
                                            const float* __restrict__ Wqkv,
                                            u16* __restrict__ wqkvT,
                                            const float* __restrict__ Wfc,
                                            u16* __restrict__ wfcT) {
  __shared__ u16 tile[32][33];
  int bid = blockIdx.x;
  if (bid < 12288) {
    int i = bid * 256 + threadIdx.x;
    float4 v = ((const float4*)x)[i];
    ushort4 o;
    o.x = f2bf(v.x); o.y = f2bf(v.y); o.z = f2bf(v.z); o.w = f2bf(v.w);
    ((ushort4*)xz)[i] = o;
    return;
  }
  const float* in; u16* out; int C, perm, b2;
  if (bid < 14016) { b2 = bid - 12288; in = Wqkv; out = wqkvT; C = 2304; perm = 1; }
  else             { b2 = bid - 14016; in = Wfc;  out = wfcT;  C = 768;  perm = 0; }
  const int R = 768;
  int tilesC = C >> 5;
  int bc = b2 % tilesC, br = b2 / tilesC;
  int tx = threadIdx.x & 31, ty = threadIdx.x >> 5;
#pragma unroll
  for (int i = 0; i < 4; ++i)
    tile[ty + i * 8][tx] = f2bf(in[(size_t)(br * 32 + ty + i * 8) * C + bc * 32 + tx]);
  __syncthreads();
#pragma unroll
  for (int i = 0; i < 4; ++i) {
    int c = bc * 32 + ty + i * 8;
    int orow;
    if (perm) {
      int which = c % 3, h = c / 288, d = (c % 288) / 3;
      orow = which * 768 + h * 96 + d;
    } else {
      orow = c;
    }
    out[(size_t)orow * R + br * 32 + tx] = tile[tx][ty + i * 8];
  }
}

// ---------------------------------------------------------------------------
// 256 x (64*NF) GEMM, BK=64, 8 waves (2 x 4), dbuf=2, 4 phases/tile:
// {ds_reads; stage-half; barrier; lgkmcnt(0)+sched_barrier; prio1 MFMA prio0;
//  barrier}, one vmcnt(0) per tile boundary. XOR-swizzled LDS (both sides).
// NF = 16-col fragments per wave (4 -> 256-wide tile, 3 -> 192-wide).
// EPI=0: bf16 store to one of {q,k,v} dense [M][768] by column region
//        (region = tc*NF/12: 768 output cols per region).
// EPI=1: fp32 store + bias; BT advanced per 1024-row batch by bstride.
template <int EPI, int NF>
__global__ __launch_bounds__(512, 2) void gemm256(
    const u16* __restrict__ A, const u16* __restrict__ BT,
    const float* __restrict__ bias, int K, int lda, int ldb, int ldc,
    int tilesN, int cpx, size_t bstride, float* __restrict__ outf,
    u16* __restrict__ q_dst, u16* __restrict__ k_dst, u16* __restrict__ v_dst) {
  __shared__ u16 As[2][16384];        // [buf][256r][64c]
  __shared__ u16 Bs[2][NF * 4096];    // [buf][64*NF r][64c]
  const int bid = blockIdx.x;
  const int swz = (bid & 7) * cpx + (bid >> 3);
  const int tr = swz / tilesN, tc = swz % tilesN;
  const int tid = threadIdx.x, lane = tid & 63, wv = tid >> 6;
  const int wr = wv >> 2, wc = wv & 3;
  const int l15 = lane & 15, lhi = lane >> 4;
  const int nt = K >> 6;
  const int region = (tc * NF) / 12;            // EPI=0: 0=q,1=k,2=v

  BT += (size_t)((unsigned)(tr * 256) >> 10) * bstride;   // per-batch B (EPI=1)

  const u16 *srcA[4], *srcB[NF];
#pragma unroll
  for (int ch = 0; ch < 4; ++ch) {
    int g = ch * 512 + tid;
    int r = g >> 3;
    int c = (g & 7) ^ ((r >> 1) & 7);
    srcA[ch] = A + (size_t)(tr * 256 + r) * lda + c * 8;
  }
#pragma unroll
  for (int ch = 0; ch < NF; ++ch) {
    int g = ch * 512 + tid;
    int r = g >> 3;
    int c = (g & 7) ^ ((r >> 1) & 7);
    srcB[ch] = BT + (size_t)(tc * (64 * NF) + r) * ldb + c * 8;
  }
  int offa[8], offb[NF];
#pragma unroll
  for (int m = 0; m < 8; ++m) {
    int r = wr * 128 + m * 16 + l15;
    offa[m] = r * 64 + (lhi ^ ((r >> 1) & 7)) * 8;
  }
#pragma unroll
  for (int n = 0; n < NF; ++n) {
    int r = wc * (16 * NF) + n * 16 + l15;
    offb[n] = r * 64 + (lhi ^ ((r >> 1) & 7)) * 8;
  }

  float bv4[NF];
#pragma unroll
  for (int n = 0; n < NF; ++n) {
    int colg = tc * (64 * NF) + wc * (16 * NF) + n * 16 + l15;
    if constexpr (EPI == 0) {
      int lcol = colg - region * 768;
      bv4[n] = bias[(lcol / 96) * 288 + (lcol % 96) * 3 + region];
    } else {
      bv4[n] = bias[colg];
    }
  }

#define STAGE_A(t_) do { u16* Ad_ = (u16*)As[(t_) & 1]; int ko_ = (t_) * 64; \
    _Pragma("unroll") for (int ch = 0; ch < 4; ++ch) \
      GLD16(srcA[ch] + ko_, Ad_ + ((ch * 512 + wv * 64) * 8)); } while (0)
#define STAGE_B(t_) do { u16* Bd_ = (u16*)Bs[(t_) & 1]; int ko_ = (t_) * 64; \
    _Pragma("unroll") for (int ch = 0; ch < NF; ++ch) \
      GLD16(srcB[ch] + ko_, Bd_ + ((ch * 512 + wv * 64) * 8)); } while (0)

  bf16x8 af[4][2], bfv[NF][2];
#define RD_A(m_, slot_) do { \
    af[slot_][0] = *(const bf16x8*)&Ab[offa[m_]]; \
    af[slot_][1] = *(const bf16x8*)&Ab[offa[m_] ^ 32]; } while (0)
#define RD_B(n_) do { \
    bfv[n_][0] = *(const bf16x8*)&Bb[offb[n_]]; \
    bfv[n_][1] = *(const bf16x8*)&Bb[offb[n_] ^ 32]; } while (0)

  f32x4 acc[8][NF] = {};
#define CLUSTER(MB, NB, NN) do { \
    __builtin_amdgcn_s_setprio(1); \
    _Pragma("unroll") for (int mm = 0; mm < 4; ++mm) \
    _Pragma("unroll") for (int nn = 0; nn < (NN); ++nn) \
    _Pragma("unroll") for (int ks = 0; ks < 2; ++ks) \
      acc[(MB) + mm][(NB) + nn] = __builtin_amdgcn_mfma_f32_16x16x32_bf16( \
          af[mm][ks], bfv[(NB) + nn][ks], acc[(MB) + mm][(NB) + nn], 0, 0, 0); \
    __builtin_amdgcn_s_setprio(0); } while (0)
#define WAIT_LGKM_PIN() do { \
    asm volatile("s_waitcnt lgkmcnt(0)" ::: "memory"); \
    __builtin_amdgcn_sched_barrier(0); } while (0)

  STAGE_A(0); STAGE_B(0);
  asm volatile("s_waitcnt vmcnt(0)" ::: "memory");
  __builtin_amdgcn_s_barrier();

  for (int t = 0; t < nt; ++t) {
    const u16* Ab = As[t & 1];
    const u16* Bb = Bs[t & 1];
    // ---- Ph0: reads A0-3,B0-1 before the barrier; stage A-half
    RD_A(0, 0); RD_A(1, 1); RD_A(2, 2); RD_A(3, 3);
    RD_B(0); RD_B(1);
    if (t + 1 < nt) STAGE_A(t + 1);
    asm volatile("s_waitcnt lgkmcnt(8)" ::: "memory");
    __builtin_amdgcn_s_barrier();
    WAIT_LGKM_PIN();
    CLUSTER(0, 0, 2);
    __builtin_amdgcn_s_barrier();
    // ---- Ph1: reads B2..NF-1; stage B-half
#pragma unroll
    for (int n = 2; n < NF; ++n) RD_B(n);
    if (t + 1 < nt) STAGE_B(t + 1);
    __builtin_amdgcn_s_barrier();
    WAIT_LGKM_PIN();
    CLUSTER(0, 2, NF - 2);
    __builtin_amdgcn_s_barrier();
    // ---- Ph2: reads A4-7
    RD_A(4, 0); RD_A(5, 1); RD_A(6, 2); RD_A(7, 3);
    __builtin_amdgcn_s_barrier();
    WAIT_LGKM_PIN();
    CLUSTER(4, 0, 2);
    __builtin_amdgcn_s_barrier();
    // ---- Ph3: last cluster; tile-boundary certification
    CLUSTER(4, 2, NF - 2);
    asm volatile("s_waitcnt vmcnt(0)" ::: "memory");
    __builtin_amdgcn_s_barrier();
  }
#undef STAGE_A
#undef STAGE_B
#undef RD_A
#undef RD_B
#undef CLUSTER
#undef WAIT_LGKM_PIN

  u16* dst16 = region == 0 ? q_dst : (region == 1 ? k_dst : v_dst);
#pragma unroll
  for (int m = 0; m < 8; ++m)
#pragma unroll
    for (int n = 0; n < NF; ++n) {
      int colg = tc * (64 * NF) + wc * (16 * NF) + n * 16 + l15;
      int lcol = colg - region * 768;
#pragma unroll
      for (int r = 0; r < 4; ++r) {
        int rowg = tr * 256 + wr * 128 + m * 16 + lhi * 4 + r;
        if constexpr (EPI == 0)
          dst16[(size_t)rowg * ldc + lcol] = f2bf(acc[m][n][r] + bv4[n]);
        else
          outf[(size_t)rowg * ldc + colg] = acc[m][n][r] + bv4[n];
      }
    }
}

// ---------------------------------------------------------------------------
// Fused K/V transpose + M = K^T V.
// Grid 256 = bh(128) x d-half(2); 128 threads (2 waves).
__global__ __launch_bounds__(128) void kvm(const u16* __restrict__ kd,
                                           const u16* __restrict__ vd,
                                           u16* __restrict__ M) {
  __shared__ u16 kT[48][136];
  __shared__ u16 vT[96][136];
  const int bh = blockIdx.x >> 1, dh = blockIdx.x & 1;
  const int b = bh >> 3, h = bh & 7;
  const int tid = threadIdx.x, lane = tid & 63, nh = tid >> 6;  // wave = n-half
  const int l15 = lane & 15, lhi = lane >> 4;

  f32x4 acc[3][3] = {};

  for (int c = 0; c < 8; ++c) {
    const u16* kbase = kd + ((size_t)(b * 1024 + c * 128)) * 768 + h * 96 + dh * 48;
    const u16* vbase = vd + ((size_t)(b * 1024 + c * 128)) * 768 + h * 96;
    __syncthreads();   // previous chunk's MFMA reads done before overwrite
#pragma unroll
    for (int j = 0; j < 6; ++j) {           // K-half: 128 rows x 6 granules
      int idx = j * 128 + tid;
      int n = idx / 6, gg = idx % 6;
      uint4 v = *(const uint4*)(kbase + (size_t)n * 768 + gg * 8);
      const u16* e = (const u16*)&v;
#pragma unroll
      for (int q = 0; q < 8; ++q) kT[gg * 8 + q][n] = e[q];
    }
#pragma unroll
    for (int j = 0; j < 12; ++j) {          // V: 128 rows x 12 granules
      int idx = j * 128 + tid;
      int n = idx / 12, gg = idx % 12;
      uint4 v = *(const uint4*)(vbase + (size_t)n * 768 + gg * 8);
      const u16* e = (const u16*)&v;
#pragma unroll
      for (int q = 0; q < 8; ++q) vT[gg * 8 + q][n] = e[q];
    }
    __syncthreads();
#pragma unroll
    for (int ks = 0; ks < 4; ++ks) {
      bf16x8 a[3], bv[3];
#pragma unroll
      for (int mi = 0; mi < 3; ++mi)
        a[mi] = *(const bf16x8*)&kT[mi * 16 + l15][ks * 32 + lhi * 8];
#pragma unroll
      for (int nj = 0; nj < 3; ++nj)
        bv[nj] = *(const bf16x8*)&vT[nh * 48 + nj * 16 + l15][ks * 32 + lhi * 8];
#pragma unroll
      for (int mi = 0; mi < 3; ++mi)
#pragma unroll
        for (int nj = 0; nj < 3; ++nj)
          acc[mi][nj] = __builtin_amdgcn_mfma_f32_16x16x32_bf16(a[mi], bv[nj], acc[mi][nj], 0, 0, 0);
    }
  }

#pragma unroll
  for (int mi = 0; mi < 3; ++mi)
#pragma unroll
    for (int nj = 0; nj < 3; ++nj)
#pragma unroll
      for (int r = 0; r < 4; ++r)
        M[(size_t)bh * 9216 + (size_t)(dh * 48 + mi * 16 + lhi * 4 + r) * 96 +
          nh * 48 + nj * 16 + l15] = f2bf(acc[mi][nj][r]);
}

// ---------------------------------------------------------------------------
// GT[b][f][h*96+d] = sum_{d'} Wfc[h*96+d', f] * M[bh][d][d']
__global__ __launch_bounds__(512) void gkern(const u16* __restrict__ wfcT,
                                             const u16* __restrict__ M,
                                             u16* __restrict__ GT) {
  const int bh = blockIdx.x;
  const int b = bh >> 3, h = bh & 7;
  const int tid = threadIdx.x, lane = tid & 63, wv = tid >> 6;
  const int l15 = lane & 15, lhi = lane >> 4;
  const u16* Mb = M + (size_t)bh * 9216;
  f32x4 acc[6][6] = {};
#pragma unroll
  for (int ks = 0; ks < 3; ++ks) {
    bf16x8 a[6], bv[6];
#pragma unroll
    for (int fi = 0; fi < 6; ++fi)
      a[fi] = *(const bf16x8*)(wfcT + (size_t)(wv * 96 + fi * 16 + l15) * 768 +
                               h * 96 + ks * 32 + lhi * 8);
#pragma unroll
    for (int nj = 0; nj < 6; ++nj)
      bv[nj] = *(const bf16x8*)(Mb + (size_t)(nj * 16 + l15) * 96 + ks * 32 + lhi * 8);
#pragma unroll
    for (int fi = 0; fi < 6; ++fi)
#pragma unroll
      for (int nj = 0; nj < 6; ++nj)
        acc[fi][nj] = __builtin_amdgcn_mfma_f32_16x16x32_bf16(a[fi], bv[nj], acc[fi][nj], 0, 0, 0);
  }
#pragma unroll
  for (int fi = 0; fi < 6; ++fi)
#pragma unroll
    for (int nj = 0; nj < 6; ++nj)
#pragma unroll
      for (int r = 0; r < 4; ++r)
        GT[(size_t)b * 589824 + (size_t)(wv * 96 + fi * 16 + lhi * 4 + r) * 768 +
           h * 96 + nj * 16 + l15] = f2bf(acc[fi][nj][r]);
}

// ---------------------------------------------------------------------------
extern "C" void kernel_launch(void* const* d_in, const int* in_sizes, int n_in,
                              void* d_out, int out_size, void* d_ws, size_t ws_size,
                              hipStream_t stream) {
  const float* x    = (const float*)d_in[0];
  const float* Wqkv = (const float*)d_in[1];
  const float* bqkv = (const float*)d_in[2];
  const float* Wfc  = (const float*)d_in[3];
  const float* bfc  = (const float*)d_in[4];
  float* out = (float*)d_out;

  char* ws = (char*)d_ws;
  size_t off = 0;
  auto alloc = [&](size_t bytes) {
    void* p = ws + off;
    off += (bytes + 255) & ~(size_t)255;
    return p;
  };
  u16* xz    = (u16*)alloc(16384ull * 768 * 2);   // x_bf16 (dead after QKV GEMM)
  u16* wqkvT = (u16*)alloc(2304ull * 768 * 2);    // later M[128][96][96]
  u16* wfcT  = (u16*)alloc(768ull * 768 * 2);
  u16* qb    = (u16*)alloc(16384ull * 768 * 2);   // Q dense
  u16* kb    = (u16*)alloc(16384ull * 768 * 2);   // K dense
  u16* vb    = (u16*)alloc(16384ull * 768 * 2);   // V dense; later GT[16][768][768]

  // fused conversions/transposes
  prep<<<14592, 256, 0, stream>>>(x, xz, Wqkv, wqkvT, Wfc, wfcT);

  // QKV projection -> dense q/k/v (256x192 tiles, 768 blocks = exactly 3/CU)
  gemm256<0, 3><<<768, 512, 0, stream>>>(xz, wqkvT, bqkv, 768, 768, 768, 768,
                                         12, 96, 0, nullptr, qb, kb, vb);

  // fused K/V transpose + M = K^T V   (M into the dead wqkvT region)
  kvm<<<256, 128, 0, stream>>>(kb, vb, (u16*)wqkvT);

  // GT_b = (M W_h)^T   (into vb, V dense dead after kvm)
  gkern<<<128, 512, 0, stream>>>(wfcT, (u16*)wqkvT, vb);

  // out = Q @ GT_b^T + bfc (per-batch B), 256x192 tiles -> 256 blocks, 1 round
  gemm256<1, 3><<<256, 512, 0, stream>>>(qb, vb, bfc, 768, 768, 768, 768,
                                         4, 32, 589824ull, out, nullptr, nullptr, nullptr);
}

// Round 15
// 146.759 us; speedup vs baseline: 1.1357x; 1.0832x over previous
//
#include <hip/hip_runtime.h>

typedef unsigned short u16;
typedef __attribute__((ext_vector_type(8))) __bf16 bf16x8;
typedef __attribute__((ext_vector_type(4))) float f32x4;

__device__ __forceinline__ u16 f2bf(float f) {
  union { float f; unsigned u; } x; x.f = f;
  unsigned r = x.u + 0x7fffu + ((x.u >> 16) & 1u);
  return (u16)(r >> 16);
}

#define GLD16(g, l) __builtin_amdgcn_global_load_lds( \
    (__attribute__((address_space(1))) void*)(size_t)(g), \
    (__attribute__((address_space(3))) void*)(l), 16, 0, 0)

// ---------------------------------------------------------------------------
// Fused prep: [0,12288) x fp32->bf16; [12288,14016) Wqkv transpose+perm;
// [14016,14592) Wfc transpose.
__global__ __launch_bounds__(256) void prep(const float* __restrict__ x,
                                            u16* __restrict__ xz,
                                            const float* __restrict__ Wqkv,
                                            u16* __restrict__ wqkvT,
                                            const float* __restrict__ Wfc,
                                            u16* __restrict__ wfcT) {
  __shared__ u16 tile[32][33];
  int bid = blockIdx.x;
  if (bid < 12288) {
    int i = bid * 256 + threadIdx.x;
    float4 v = ((const float4*)x)[i];
    ushort4 o;
    o.x = f2bf(v.x); o.y = f2bf(v.y); o.z = f2bf(v.z); o.w = f2bf(v.w);
    ((ushort4*)xz)[i] = o;
    return;
  }
  const float* in; u16* out; int C, perm, b2;
  if (bid < 14016) { b2 = bid - 12288; in = Wqkv; out = wqkvT; C = 2304; perm = 1; }
  else             { b2 = bid - 14016; in = Wfc;  out = wfcT;  C = 768;  perm = 0; }
  const int R = 768;
  int tilesC = C >> 5;
  int bc = b2 % tilesC, br = b2 / tilesC;
  int tx = threadIdx.x & 31, ty = threadIdx.x >> 5;
#pragma unroll
  for (int i = 0; i < 4; ++i)
    tile[ty + i * 8][tx] = f2bf(in[(size_t)(br * 32 + ty + i * 8) * C + bc * 32 + tx]);
  __syncthreads();
#pragma unroll
  for (int i = 0; i < 4; ++i) {
    int c = bc * 32 + ty + i * 8;
    int orow;
    if (perm) {
      int which = c % 3, h = c / 288, d = (c % 288) / 3;
      orow = which * 768 + h * 96 + d;
    } else {
      orow = c;
    }
    out[(size_t)orow * R + br * 32 + tx] = tile[tx][ty + i * 8];
  }
}

// ---------------------------------------------------------------------------
// 128 x 192 GEMM tile, BK=64, 8 waves (2 x 4, wave = 64x48), dbuf=2,
// 2 phases/tile (same body style as the proven 4-phase template).
// LDS = 80 KB exactly -> 2 blocks/CU co-resident: inter-block overlap covers
// the barrier/drain stalls that capped the 1-block/CU variants.
// __launch_bounds__(512,4) caps VGPR at 128 so 2 blocks actually fit.
// EPI=0: bf16 store to one of {q,k,v} dense [M][768] by region tc/4.
// EPI=1: fp32 store + bias; BT advanced per 1024-row batch by bstride.
template <int EPI>
__global__ __launch_bounds__(512, 4) void gemm128(
    const u16* __restrict__ A, const u16* __restrict__ BT,
    const float* __restrict__ bias, int K, int lda, int ldb, int ldc,
    int tilesN, int cpx, size_t bstride, float* __restrict__ outf,
    u16* __restrict__ q_dst, u16* __restrict__ k_dst, u16* __restrict__ v_dst) {
  __shared__ u16 As[2][8192];    // [buf][128r][64c] = 32 KB
  __shared__ u16 Bs[2][12288];   // [buf][192r][64c] = 48 KB
  const int bid = blockIdx.x;
  const int swz = (bid & 7) * cpx + (bid >> 3);
  const int tr = swz / tilesN, tc = swz % tilesN;
  const int tid = threadIdx.x, lane = tid & 63, wv = tid >> 6;
  const int wr = wv >> 2, wc = wv & 3;          // wave -> 64x48 sub-tile
  const int l15 = lane & 15, lhi = lane >> 4;
  const int nt = K >> 6;
  const int region = tc >> 2;                   // EPI=0 (tilesN=12): 0=q,1=k,2=v

  BT += (size_t)((unsigned)(tr * 128) >> 10) * bstride;   // per-batch B (EPI=1)

  const u16 *srcA[2], *srcB[3];
#pragma unroll
  for (int ch = 0; ch < 2; ++ch) {
    int g = ch * 512 + tid;
    int r = g >> 3;
    int c = (g & 7) ^ ((r >> 1) & 7);
    srcA[ch] = A + (size_t)(tr * 128 + r) * lda + c * 8;
  }
#pragma unroll
  for (int ch = 0; ch < 3; ++ch) {
    int g = ch * 512 + tid;
    int r = g >> 3;
    int c = (g & 7) ^ ((r >> 1) & 7);
    srcB[ch] = BT + (size_t)(tc * 192 + r) * ldb + c * 8;
  }
  int offa[4], offb[3];
#pragma unroll
  for (int m = 0; m < 4; ++m) {
    int r = wr * 64 + m * 16 + l15;
    offa[m] = r * 64 + (lhi ^ ((r >> 1) & 7)) * 8;
  }
#pragma unroll
  for (int n = 0; n < 3; ++n) {
    int r = wc * 48 + n * 16 + l15;
    offb[n] = r * 64 + (lhi ^ ((r >> 1) & 7)) * 8;
  }

  float bv3[3];
#pragma unroll
  for (int n = 0; n < 3; ++n) {
    int colg = tc * 192 + wc * 48 + n * 16 + l15;
    if constexpr (EPI == 0) {
      int lcol = colg - region * 768;
      bv3[n] = bias[(lcol / 96) * 288 + (lcol % 96) * 3 + region];
    } else {
      bv3[n] = bias[colg];
    }
  }

#define STAGE_A(t_) do { u16* Ad_ = (u16*)As[(t_) & 1]; int ko_ = (t_) * 64; \
    _Pragma("unroll") for (int ch = 0; ch < 2; ++ch) \
      GLD16(srcA[ch] + ko_, Ad_ + ((ch * 512 + wv * 64) * 8)); } while (0)
#define STAGE_B(t_) do { u16* Bd_ = (u16*)Bs[(t_) & 1]; int ko_ = (t_) * 64; \
    _Pragma("unroll") for (int ch = 0; ch < 3; ++ch) \
      GLD16(srcB[ch] + ko_, Bd_ + ((ch * 512 + wv * 64) * 8)); } while (0)

  bf16x8 af[2][2], bfv[3][2];
#define RD_A(m_, slot_) do { \
    af[slot_][0] = *(const bf16x8*)&Ab[offa[m_]]; \
    af[slot_][1] = *(const bf16x8*)&Ab[offa[m_] ^ 32]; } while (0)
#define RD_B(n_) do { \
    bfv[n_][0] = *(const bf16x8*)&Bb[offb[n_]]; \
    bfv[n_][1] = *(const bf16x8*)&Bb[offb[n_] ^ 32]; } while (0)

  f32x4 acc[4][3] = {};
  // 12 MFMA: acc rows MB..MB+1 x 3 n-frags x 2 k-slices (af slots 0,1)
#define CLUSTER12(MB) do { \
    __builtin_amdgcn_s_setprio(1); \
    _Pragma("unroll") for (int mm = 0; mm < 2; ++mm) \
    _Pragma("unroll") for (int nn = 0; nn < 3; ++nn) \
    _Pragma("unroll") for (int ks = 0; ks < 2; ++ks) \
      acc[(MB) + mm][nn] = __builtin_amdgcn_mfma_f32_16x16x32_bf16( \
          af[mm][ks], bfv[nn][ks], acc[(MB) + mm][nn], 0, 0, 0); \
    __builtin_amdgcn_s_setprio(0); } while (0)
#define WAIT_LGKM_PIN() do { \
    asm volatile("s_waitcnt lgkmcnt(0)" ::: "memory"); \
    __builtin_amdgcn_sched_barrier(0); } while (0)

  STAGE_A(0); STAGE_B(0);
  asm volatile("s_waitcnt vmcnt(0)" ::: "memory");
  __builtin_amdgcn_s_barrier();

  for (int t = 0; t < nt; ++t) {
    const u16* Ab = As[t & 1];
    const u16* Bb = Bs[t & 1];
    // ---- Ph0: reads A0-1 + all B before the barrier; stage A-half
    RD_A(0, 0); RD_A(1, 1);
    RD_B(0); RD_B(1); RD_B(2);
    if (t + 1 < nt) STAGE_A(t + 1);
    __builtin_amdgcn_s_barrier();
    WAIT_LGKM_PIN();
    CLUSTER12(0);
    __builtin_amdgcn_s_barrier();
    // ---- Ph1: reads A2-3; stage B-half; tile-boundary certification
    RD_A(2, 0); RD_A(3, 1);
    if (t + 1 < nt) STAGE_B(t + 1);
    __builtin_amdgcn_s_barrier();
    WAIT_LGKM_PIN();
    CLUSTER12(2);
    asm volatile("s_waitcnt vmcnt(0)" ::: "memory");
    __builtin_amdgcn_s_barrier();
  }
#undef STAGE_A
#undef STAGE_B
#undef RD_A
#undef RD_B
#undef CLUSTER12
#undef WAIT_LGKM_PIN

  u16* dst16 = region == 0 ? q_dst : (region == 1 ? k_dst : v_dst);
#pragma unroll
  for (int m = 0; m < 4; ++m)
#pragma unroll
    for (int n = 0; n < 3; ++n) {
      int colg = tc * 192 + wc * 48 + n * 16 + l15;
      int lcol = colg - region * 768;
#pragma unroll
      for (int r = 0; r < 4; ++r) {
        int rowg = tr * 128 + wr * 64 + m * 16 + lhi * 4 + r;
        if constexpr (EPI == 0)
          dst16[(size_t)rowg * ldc + lcol] = f2bf(acc[m][n][r] + bv3[n]);
        else
          outf[(size_t)rowg * ldc + colg] = acc[m][n][r] + bv3[n];
      }
    }
}

// ---------------------------------------------------------------------------
// Fused K/V transpose + M = K^T V.
// Grid 256 = bh(128) x d-half(2); 128 threads (2 waves).
__global__ __launch_bounds__(128) void kvm(const u16* __restrict__ kd,
                                           const u16* __restrict__ vd,
                                           u16* __restrict__ M) {
  __shared__ u16 kT[48][136];
  __shared__ u16 vT[96][136];
  const int bh = blockIdx.x >> 1, dh = blockIdx.x & 1;
  const int b = bh >> 3, h = bh & 7;
  const int tid = threadIdx.x, lane = tid & 63, nh = tid >> 6;  // wave = n-half
  const int l15 = lane & 15, lhi = lane >> 4;

  f32x4 acc[3][3] = {};

  for (int c = 0; c < 8; ++c) {
    const u16* kbase = kd + ((size_t)(b * 1024 + c * 128)) * 768 + h * 96 + dh * 48;
    const u16* vbase = vd + ((size_t)(b * 1024 + c * 128)) * 768 + h * 96;
    __syncthreads();   // previous chunk's MFMA reads done before overwrite
#pragma unroll
    for (int j = 0; j < 6; ++j) {           // K-half: 128 rows x 6 granules
      int idx = j * 128 + tid;
      int n = idx / 6, gg = idx % 6;
      uint4 v = *(const uint4*)(kbase + (size_t)n * 768 + gg * 8);
      const u16* e = (const u16*)&v;
#pragma unroll
      for (int q = 0; q < 8; ++q) kT[gg * 8 + q][n] = e[q];
    }
#pragma unroll
    for (int j = 0; j < 12; ++j) {          // V: 128 rows x 12 granules
      int idx = j * 128 + tid;
      int n = idx / 12, gg = idx % 12;
      uint4 v = *(const uint4*)(vbase + (size_t)n * 768 + gg * 8);
      const u16* e = (const u16*)&v;
#pragma unroll
      for (int q = 0; q < 8; ++q) vT[gg * 8 + q][n] = e[q];
    }
    __syncthreads();
#pragma unroll
    for (int ks = 0; ks < 4; ++ks) {
      bf16x8 a[3], bv[3];
#pragma unroll
      for (int mi = 0; mi < 3; ++mi)
        a[mi] = *(const bf16x8*)&kT[mi * 16 + l15][ks * 32 + lhi * 8];
#pragma unroll
      for (int nj = 0; nj < 3; ++nj)
        bv[nj] = *(const bf16x8*)&vT[nh * 48 + nj * 16 + l15][ks * 32 + lhi * 8];
#pragma unroll
      for (int mi = 0; mi < 3; ++mi)
#pragma unroll
        for (int nj = 0; nj < 3; ++nj)
          acc[mi][nj] = __builtin_amdgcn_mfma_f32_16x16x32_bf16(a[mi], bv[nj], acc[mi][nj], 0, 0, 0);
    }
  }

#pragma unroll
  for (int mi = 0; mi < 3; ++mi)
#pragma unroll
    for (int nj = 0; nj < 3; ++nj)
#pragma unroll
      for (int r = 0; r < 4; ++r)
        M[(size_t)bh * 9216 + (size_t)(dh * 48 + mi * 16 + lhi * 4 + r) * 96 +
          nh * 48 + nj * 16 + l15] = f2bf(acc[mi][nj][r]);
}

// ---------------------------------------------------------------------------
// GT[b][f][h*96+d] = sum_{d'} Wfc[h*96+d', f] * M[bh][d][d']
__global__ __launch_bounds__(512) void gkern(const u16* __restrict__ wfcT,
                                             const u16* __restrict__ M,
                                             u16* __restrict__ GT) {
  const int bh = blockIdx.x;
  const int b = bh >> 3, h = bh & 7;
  const int tid = threadIdx.x, lane = tid & 63, wv = tid >> 6;
  const int l15 = lane & 15, lhi = lane >> 4;
  const u16* Mb = M + (size_t)bh * 9216;
  f32x4 acc[6][6] = {};
#pragma unroll
  for (int ks = 0; ks < 3; ++ks) {
    bf16x8 a[6], bv[6];
#pragma unroll
    for (int fi = 0; fi < 6; ++fi)
      a[fi] = *(const bf16x8*)(wfcT + (size_t)(wv * 96 + fi * 16 + l15) * 768 +
                               h * 96 + ks * 32 + lhi * 8);
#pragma unroll
    for (int nj = 0; nj < 6; ++nj)
      bv[nj] = *(const bf16x8*)(Mb + (size_t)(nj * 16 + l15) * 96 + ks * 32 + lhi * 8);
#pragma unroll
    for (int fi = 0; fi < 6; ++fi)
#pragma unroll
      for (int nj = 0; nj < 6; ++nj)
        acc[fi][nj] = __builtin_amdgcn_mfma_f32_16x16x32_bf16(a[fi], bv[nj], acc[fi][nj], 0, 0, 0);
  }
#pragma unroll
  for (int fi = 0; fi < 6; ++fi)
#pragma unroll
    for (int nj = 0; nj < 6; ++nj)
#pragma unroll
      for (int r = 0; r < 4; ++r)
        GT[(size_t)b * 589824 + (size_t)(wv * 96 + fi * 16 + lhi * 4 + r) * 768 +
           h * 96 + nj * 16 + l15] = f2bf(acc[fi][nj][r]);
}

// ---------------------------------------------------------------------------
extern "C" void kernel_launch(void* const* d_in, const int* in_sizes, int n_in,
                              void* d_out, int out_size, void* d_ws, size_t ws_size,
                              hipStream_t stream) {
  const float* x    = (const float*)d_in[0];
  const float* Wqkv = (const float*)d_in[1];
  const float* bqkv = (const float*)d_in[2];
  const float* Wfc  = (const float*)d_in[3];
  const float* bfc  = (const float*)d_in[4];
  float* out = (float*)d_out;

  char* ws = (char*)d_ws;
  size_t off = 0;
  auto alloc = [&](size_t bytes) {
    void* p = ws + off;
    off += (bytes + 255) & ~(size_t)255;
    return p;
  };
  u16* xz    = (u16*)alloc(16384ull * 768 * 2);   // x_bf16 (dead after QKV GEMM)
  u16* wqkvT = (u16*)alloc(2304ull * 768 * 2);    // later M[128][96][96]
  u16* wfcT  = (u16*)alloc(768ull * 768 * 2);
  u16* qb    = (u16*)alloc(16384ull * 768 * 2);   // Q dense
  u16* kb    = (u16*)alloc(16384ull * 768 * 2);   // K dense
  u16* vb    = (u16*)alloc(16384ull * 768 * 2);   // V dense; later GT[16][768][768]

  // fused conversions/transposes
  prep<<<14592, 256, 0, stream>>>(x, xz, Wqkv, wqkvT, Wfc, wfcT);

  // QKV projection -> dense q/k/v (128x192 tiles, 1536 blocks = 6 rounds,
  // 2 blocks/CU co-resident)
  gemm128<0><<<1536, 512, 0, stream>>>(xz, wqkvT, bqkv, 768, 768, 768, 768,
                                       12, 192, 0, nullptr, qb, kb, vb);

  // fused K/V transpose + M = K^T V   (M into the dead wqkvT region)
  kvm<<<256, 128, 0, stream>>>(kb, vb, (u16*)wqkvT);

  // GT_b = (M W_h)^T   (into vb, V dense dead after kvm)
  gkern<<<128, 512, 0, stream>>>(wfcT, (u16*)wqkvT, vb);

  // out = Q @ GT_b^T + bfc (per-batch B), 128x192 tiles -> 512 blocks, 2 rounds
  gemm128<1><<<512, 512, 0, stream>>>(qb, vb, bfc, 768, 768, 768, 768,
                                      4, 64, 589824ull, out, nullptr, nullptr, nullptr);
}

// Round 16
// 145.595 us; speedup vs baseline: 1.1448x; 1.0080x over previous
//
#include <hip/hip_runtime.h>

typedef unsigned short u16;
typedef __attribute__((ext_vector_type(8))) __bf16 bf16x8;
typedef __attribute__((ext_vector_type(4))) float f32x4;

__device__ __forceinline__ u16 f2bf(float f) {
  union { float f; unsigned u; } x; x.f = f;
  unsigned r = x.u + 0x7fffu + ((x.u >> 16) & 1u);
  return (u16)(r >> 16);
}

#define GLD16(g, l) __builtin_amdgcn_global_load_lds( \
    (__attribute__((address_space(1))) void*)(size_t)(g), \
    (__attribute__((address_space(3))) void*)(l), 16, 0, 0)

// ---------------------------------------------------------------------------
// Fused prep: [0,12288) x fp32->bf16; [12288,14016) Wqkv transpose+perm;
// [14016,14592) Wfc transpose.
__global__ __launch_bounds__(256) void prep(const float* __restrict__ x,
                                            u16* __restrict__ xz,
                                            const float* __restrict__ Wqkv,
                                            u16* __restrict__ wqkvT,
                                            const float* __restrict__ Wfc,
                                            u16* __restrict__ wfcT) {
  __shared__ u16 tile[32][33];
  int bid = blockIdx.x;
  if (bid < 12288) {
    int i = bid * 256 + threadIdx.x;
    float4 v = ((const float4*)x)[i];
    ushort4 o;
    o.x = f2bf(v.x); o.y = f2bf(v.y); o.z = f2bf(v.z); o.w = f2bf(v.w);
    ((ushort4*)xz)[i] = o;
    return;
  }
  const float* in; u16* out; int C, perm, b2;
  if (bid < 14016) { b2 = bid - 12288; in = Wqkv; out = wqkvT; C = 2304; perm = 1; }
  else             { b2 = bid - 14016; in = Wfc;  out = wfcT;  C = 768;  perm = 0; }
  const int R = 768;
  int tilesC = C >> 5;
  int bc = b2 % tilesC, br = b2 / tilesC;
  int tx = threadIdx.x & 31, ty = threadIdx.x >> 5;
#pragma unroll
  for (int i = 0; i < 4; ++i)
    tile[ty + i * 8][tx] = f2bf(in[(size_t)(br * 32 + ty + i * 8) * C + bc * 32 + tx]);
  __syncthreads();
#pragma unroll
  for (int i = 0; i < 4; ++i) {
    int c = bc * 32 + ty + i * 8;
    int orow;
    if (perm) {
      int which = c % 3, h = c / 288, d = (c % 288) / 3;
      orow = which * 768 + h * 96 + d;
    } else {
      orow = c;
    }
    out[(size_t)orow * R + br * 32 + tx] = tile[tx][ty + i * 8];
  }
}

// ---------------------------------------------------------------------------
// 128 x 192 GEMM tile, BK=64, 8 waves (2 x 4, wave = 64x48), dbuf=2,
// SINGLE barrier + single vmcnt(0) per K-tile: all intra-tile ordering is
// per-wave lgkmcnt; the boundary {vmcnt(0); barrier} is the only collective.
// Hazard ledger: RAW stage(t): vmcnt(0) precedes the boundary barrier of t-1.
//   WAR stage(t+1)->buf (t-1)&1: every wave's t-1 ds_reads completed at its
//   own lgkmcnt(0) (before its t-1 MFMAs), hence before it passed the t-1
//   boundary barrier, hence before any wave issues stage(t+1) in tile t.
// LDS 80 KB -> 2 blocks/CU; af[2][2] slot reuse keeps VGPR at 64.
template <int EPI>
__global__ __launch_bounds__(512, 4) void gemm128(
    const u16* __restrict__ A, const u16* __restrict__ BT,
    const float* __restrict__ bias, int K, int lda, int ldb, int ldc,
    int tilesN, int cpx, size_t bstride, float* __restrict__ outf,
    u16* __restrict__ q_dst, u16* __restrict__ k_dst, u16* __restrict__ v_dst) {
  __shared__ u16 As[2][8192];    // [buf][128r][64c] = 32 KB
  __shared__ u16 Bs[2][12288];   // [buf][192r][64c] = 48 KB
  const int bid = blockIdx.x;
  const int swz = (bid & 7) * cpx + (bid >> 3);
  const int tr = swz / tilesN, tc = swz % tilesN;
  const int tid = threadIdx.x, lane = tid & 63, wv = tid >> 6;
  const int wr = wv >> 2, wc = wv & 3;          // wave -> 64x48 sub-tile
  const int l15 = lane & 15, lhi = lane >> 4;
  const int nt = K >> 6;
  const int region = tc >> 2;                   // EPI=0 (tilesN=12): 0=q,1=k,2=v

  BT += (size_t)((unsigned)(tr * 128) >> 10) * bstride;   // per-batch B (EPI=1)

  const u16 *srcA[2], *srcB[3];
#pragma unroll
  for (int ch = 0; ch < 2; ++ch) {
    int g = ch * 512 + tid;
    int r = g >> 3;
    int c = (g & 7) ^ ((r >> 1) & 7);
    srcA[ch] = A + (size_t)(tr * 128 + r) * lda + c * 8;
  }
#pragma unroll
  for (int ch = 0; ch < 3; ++ch) {
    int g = ch * 512 + tid;
    int r = g >> 3;
    int c = (g & 7) ^ ((r >> 1) & 7);
    srcB[ch] = BT + (size_t)(tc * 192 + r) * ldb + c * 8;
  }
  int offa[4], offb[3];
#pragma unroll
  for (int m = 0; m < 4; ++m) {
    int r = wr * 64 + m * 16 + l15;
    offa[m] = r * 64 + (lhi ^ ((r >> 1) & 7)) * 8;
  }
#pragma unroll
  for (int n = 0; n < 3; ++n) {
    int r = wc * 48 + n * 16 + l15;
    offb[n] = r * 64 + (lhi ^ ((r >> 1) & 7)) * 8;
  }

  float bv3[3];
#pragma unroll
  for (int n = 0; n < 3; ++n) {
    int colg = tc * 192 + wc * 48 + n * 16 + l15;
    if constexpr (EPI == 0) {
      int lcol = colg - region * 768;
      bv3[n] = bias[(lcol / 96) * 288 + (lcol % 96) * 3 + region];
    } else {
      bv3[n] = bias[colg];
    }
  }

#define STAGE_A(t_) do { u16* Ad_ = (u16*)As[(t_) & 1]; int ko_ = (t_) * 64; \
    _Pragma("unroll") for (int ch = 0; ch < 2; ++ch) \
      GLD16(srcA[ch] + ko_, Ad_ + ((ch * 512 + wv * 64) * 8)); } while (0)
#define STAGE_B(t_) do { u16* Bd_ = (u16*)Bs[(t_) & 1]; int ko_ = (t_) * 64; \
    _Pragma("unroll") for (int ch = 0; ch < 3; ++ch) \
      GLD16(srcB[ch] + ko_, Bd_ + ((ch * 512 + wv * 64) * 8)); } while (0)

  bf16x8 af[2][2], bfv[3][2];
#define RD_A(m_, slot_) do { \
    af[slot_][0] = *(const bf16x8*)&Ab[offa[m_]]; \
    af[slot_][1] = *(const bf16x8*)&Ab[offa[m_] ^ 32]; } while (0)
#define RD_B(n_) do { \
    bfv[n_][0] = *(const bf16x8*)&Bb[offb[n_]]; \
    bfv[n_][1] = *(const bf16x8*)&Bb[offb[n_] ^ 32]; } while (0)

  f32x4 acc[4][3] = {};
  // 12 MFMA: acc rows MB..MB+1 x 3 n-frags x 2 k-slices (af slots 0,1)
#define CLUSTER12(MB) do { \
    __builtin_amdgcn_s_setprio(1); \
    _Pragma("unroll") for (int mm = 0; mm < 2; ++mm) \
    _Pragma("unroll") for (int nn = 0; nn < 3; ++nn) \
    _Pragma("unroll") for (int ks = 0; ks < 2; ++ks) \
      acc[(MB) + mm][nn] = __builtin_amdgcn_mfma_f32_16x16x32_bf16( \
          af[mm][ks], bfv[nn][ks], acc[(MB) + mm][nn], 0, 0, 0); \
    __builtin_amdgcn_s_setprio(0); } while (0)
#define WAIT_LGKM_PIN() do { \
    asm volatile("s_waitcnt lgkmcnt(0)" ::: "memory"); \
    __builtin_amdgcn_sched_barrier(0); } while (0)

  STAGE_A(0); STAGE_B(0);
  asm volatile("s_waitcnt vmcnt(0)" ::: "memory");
  __builtin_amdgcn_s_barrier();

  for (int t = 0; t < nt; ++t) {
    const u16* Ab = As[t & 1];
    const u16* Bb = Bs[t & 1];
    // issue first read group + next-tile staging; no intra-tile barriers
    RD_A(0, 0); RD_A(1, 1);
    RD_B(0); RD_B(1); RD_B(2);
    if (t + 1 < nt) { STAGE_A(t + 1); STAGE_B(t + 1); }
    WAIT_LGKM_PIN();
    CLUSTER12(0);
    RD_A(2, 0); RD_A(3, 1);
    WAIT_LGKM_PIN();
    CLUSTER12(2);
    // boundary: certify stage(t+1), collective release
    asm volatile("s_waitcnt vmcnt(0)" ::: "memory");
    __builtin_amdgcn_s_barrier();
  }
#undef STAGE_A
#undef STAGE_B
#undef RD_A
#undef RD_B
#undef CLUSTER12
#undef WAIT_LGKM_PIN

  u16* dst16 = region == 0 ? q_dst : (region == 1 ? k_dst : v_dst);
#pragma unroll
  for (int m = 0; m < 4; ++m)
#pragma unroll
    for (int n = 0; n < 3; ++n) {
      int colg = tc * 192 + wc * 48 + n * 16 + l15;
      int lcol = colg - region * 768;
#pragma unroll
      for (int r = 0; r < 4; ++r) {
        int rowg = tr * 128 + wr * 64 + m * 16 + lhi * 4 + r;
        if constexpr (EPI == 0)
          dst16[(size_t)rowg * ldc + lcol] = f2bf(acc[m][n][r] + bv3[n]);
        else
          outf[(size_t)rowg * ldc + colg] = acc[m][n][r] + bv3[n];
      }
    }
}

// ---------------------------------------------------------------------------
// Fused K/V transpose + M = K^T V.
// Grid 256 = bh(128) x d-half(2); 128 threads (2 waves).
__global__ __launch_bounds__(128) void kvm(const u16* __restrict__ kd,
                                           const u16* __restrict__ vd,
                                           u16* __restrict__ M) {
  __shared__ u16 kT[48][136];
  __shared__ u16 vT[96][136];
  const int bh = blockIdx.x >> 1, dh = blockIdx.x & 1;
  const int b = bh >> 3, h = bh & 7;
  const int tid = threadIdx.x, lane = tid & 63, nh = tid >> 6;  // wave = n-half
  const int l15 = lane & 15, lhi = lane >> 4;

  f32x4 acc[3][3] = {};

  for (int c = 0; c < 8; ++c) {
    const u16* kbase = kd + ((size_t)(b * 1024 + c * 128)) * 768 + h * 96 + dh * 48;
    const u16* vbase = vd + ((size_t)(b * 1024 + c * 128)) * 768 + h * 96;
    __syncthreads();   // previous chunk's MFMA reads done before overwrite
#pragma unroll
    for (int j = 0; j < 6; ++j) {           // K-half: 128 rows x 6 granules
      int idx = j * 128 + tid;
      int n = idx / 6, gg = idx % 6;
      uint4 v = *(const uint4*)(kbase + (size_t)n * 768 + gg * 8);
      const u16* e = (const u16*)&v;
#pragma unroll
      for (int q = 0; q < 8; ++q) kT[gg * 8 + q][n] = e[q];
    }
#pragma unroll
    for (int j = 0; j < 12; ++j) {          // V: 128 rows x 12 granules
      int idx = j * 128 + tid;
      int n = idx / 12, gg = idx % 12;
      uint4 v = *(const uint4*)(vbase + (size_t)n * 768 + gg * 8);
      const u16* e = (const u16*)&v;
#pragma unroll
      for (int q = 0; q < 8; ++q) vT[gg * 8 + q][n] = e[q];
    }
    __syncthreads();
#pragma unroll
    for (int ks = 0; ks < 4; ++ks) {
      bf16x8 a[3], bv[3];
#pragma unroll
      for (int mi = 0; mi < 3; ++mi)
        a[mi] = *(const bf16x8*)&kT[mi * 16 + l15][ks * 32 + lhi * 8];
#pragma unroll
      for (int nj = 0; nj < 3; ++nj)
        bv[nj] = *(const bf16x8*)&vT[nh * 48 + nj * 16 + l15][ks * 32 + lhi * 8];
#pragma unroll
      for (int mi = 0; mi < 3; ++mi)
#pragma unroll
        for (int nj = 0; nj < 3; ++nj)
          acc[mi][nj] = __builtin_amdgcn_mfma_f32_16x16x32_bf16(a[mi], bv[nj], acc[mi][nj], 0, 0, 0);
    }
  }

#pragma unroll
  for (int mi = 0; mi < 3; ++mi)
#pragma unroll
    for (int nj = 0; nj < 3; ++nj)
#pragma unroll
      for (int r = 0; r < 4; ++r)
        M[(size_t)bh * 9216 + (size_t)(dh * 48 + mi * 16 + lhi * 4 + r) * 96 +
          nh * 48 + nj * 16 + l15] = f2bf(acc[mi][nj][r]);
}

// ---------------------------------------------------------------------------
// GT[b][f][h*96+d] = sum_{d'} Wfc[h*96+d', f] * M[bh][d][d']
__global__ __launch_bounds__(512) void gkern(const u16* __restrict__ wfcT,
                                             const u16* __restrict__ M,
                                             u16* __restrict__ GT) {
  const int bh = blockIdx.x;
  const int b = bh >> 3, h = bh & 7;
  const int tid = threadIdx.x, lane = tid & 63, wv = tid >> 6;
  const int l15 = lane & 15, lhi = lane >> 4;
  const u16* Mb = M + (size_t)bh * 9216;
  f32x4 acc[6][6] = {};
#pragma unroll
  for (int ks = 0; ks < 3; ++ks) {
    bf16x8 a[6], bv[6];
#pragma unroll
    for (int fi = 0; fi < 6; ++fi)
      a[fi] = *(const bf16x8*)(wfcT + (size_t)(wv * 96 + fi * 16 + l15) * 768 +
                               h * 96 + ks * 32 + lhi * 8);
#pragma unroll
    for (int nj = 0; nj < 6; ++nj)
      bv[nj] = *(const bf16x8*)(Mb + (size_t)(nj * 16 + l15) * 96 + ks * 32 + lhi * 8);
#pragma unroll
    for (int fi = 0; fi < 6; ++fi)
#pragma unroll
      for (int nj = 0; nj < 6; ++nj)
        acc[fi][nj] = __builtin_amdgcn_mfma_f32_16x16x32_bf16(a[fi], bv[nj], acc[fi][nj], 0, 0, 0);
  }
#pragma unroll
  for (int fi = 0; fi < 6; ++fi)
#pragma unroll
    for (int nj = 0; nj < 6; ++nj)
#pragma unroll
      for (int r = 0; r < 4; ++r)
        GT[(size_t)b * 589824 + (size_t)(wv * 96 + fi * 16 + lhi * 4 + r) * 768 +
           h * 96 + nj * 16 + l15] = f2bf(acc[fi][nj][r]);
}

// ---------------------------------------------------------------------------
extern "C" void kernel_launch(void* const* d_in, const int* in_sizes, int n_in,
                              void* d_out, int out_size, void* d_ws, size_t ws_size,
                              hipStream_t stream) {
  const float* x    = (const float*)d_in[0];
  const float* Wqkv = (const float*)d_in[1];
  const float* bqkv = (const float*)d_in[2];
  const float* Wfc  = (const float*)d_in[3];
  const float* bfc  = (const float*)d_in[4];
  float* out = (float*)d_out;

  char* ws = (char*)d_ws;
  size_t off = 0;
  auto alloc = [&](size_t bytes) {
    void* p = ws + off;
    off += (bytes + 255) & ~(size_t)255;
    return p;
  };
  u16* xz    = (u16*)alloc(16384ull * 768 * 2);   // x_bf16 (dead after QKV GEMM)
  u16* wqkvT = (u16*)alloc(2304ull * 768 * 2);    // later M[128][96][96]
  u16* wfcT  = (u16*)alloc(768ull * 768 * 2);
  u16* qb    = (u16*)alloc(16384ull * 768 * 2);   // Q dense
  u16* kb    = (u16*)alloc(16384ull * 768 * 2);   // K dense
  u16* vb    = (u16*)alloc(16384ull * 768 * 2);   // V dense; later GT[16][768][768]

  // fused conversions/transposes
  prep<<<14592, 256, 0, stream>>>(x, xz, Wqkv, wqkvT, Wfc, wfcT);

  // QKV projection -> dense q/k/v (128x192 tiles, 1536 blocks = 6 rounds,
  // 2 blocks/CU co-resident)
  gemm128<0><<<1536, 512, 0, stream>>>(xz, wqkvT, bqkv, 768, 768, 768, 768,
                                       12, 192, 0, nullptr, qb, kb, vb);

  // fused K/V transpose + M = K^T V   (M into the dead wqkvT region)
  kvm<<<256, 128, 0, stream>>>(kb, vb, (u16*)wqkvT);

  // GT_b = (M W_h)^T   (into vb, V dense dead after kvm)
  gkern<<<128, 512, 0, stream>>>(wfcT, (u16*)wqkvT, vb);

  // out = Q @ GT_b^T + bfc (per-batch B), 128x192 tiles -> 512 blocks, 2 rounds
  gemm128<1><<<512, 512, 0, stream>>>(qb, vb, bfc, 768, 768, 768, 768,
                                      4, 64, 589824ull, out, nullptr, nullptr, nullptr);
}